// Round 2
// baseline (503.222 us; speedup 1.0000x reference)
//
#include <hip/hip_runtime.h>
#include <hip/hip_bf16.h>

typedef unsigned short u16;
typedef unsigned int u32;
typedef __attribute__((ext_vector_type(4))) unsigned int uint4v;

#define INF 128
#define OUTF 128
#define NHEAD 8
#define HDIM 16

__device__ __forceinline__ float lo2f(u32 u) { return __uint_as_float(u << 16); }
__device__ __forceinline__ float hi2f(u32 u) { return __uint_as_float(u & 0xffff0000u); }
__device__ __forceinline__ float bf2f(u16 b) { return __uint_as_float(((u32)b) << 16); }
__device__ __forceinline__ u16 f2bf(float x) {
    __hip_bfloat16 h = __float2bfloat16(x);   // RNE
    return *reinterpret_cast<u16*>(&h);
}

// load 8 consecutive float values from `base` at element offset `eoff`,
// where base is either f32 (isf32=1) or bf16 (isf32=0). eoff % 8 == 0.
__device__ __forceinline__ void load8(const void* base, size_t eoff, int isf32, float o[8]) {
    if (isf32) {
        const float* p = (const float*)base + eoff;
        float4 a = *(const float4*)p;
        float4 b = *(const float4*)(p + 4);
        o[0] = a.x; o[1] = a.y; o[2] = a.z; o[3] = a.w;
        o[4] = b.x; o[5] = b.y; o[6] = b.z; o[7] = b.w;
    } else {
        uint4v u = *(const uint4v*)((const u16*)base + eoff);
        o[0] = lo2f(u.x); o[1] = hi2f(u.x);
        o[2] = lo2f(u.y); o[3] = hi2f(u.y);
        o[4] = lo2f(u.z); o[5] = hi2f(u.z);
        o[6] = lo2f(u.w); o[7] = hi2f(u.w);
    }
}

__device__ __forceinline__ uint4v pack8(const float v[8]) {
    uint4v u;
    u.x = (u32)f2bf(v[0]) | ((u32)f2bf(v[1]) << 16);
    u.y = (u32)f2bf(v[2]) | ((u32)f2bf(v[3]) << 16);
    u.z = (u32)f2bf(v[4]) | ((u32)f2bf(v[5]) << 16);
    u.w = (u32)f2bf(v[6]) | ((u32)f2bf(v[7]) << 16);
    return u;
}

// ---------------------------------------------------------------------------
// K0: dtype detector. If feat is really f32, its low u16 halves decoded as
// bf16 have random exponents -> max blows past 1e6 (P ~ 1-1e-32 over 512
// samples). Genuine bf16 normal(0,1) data maxes ~4. Deterministic.
// ---------------------------------------------------------------------------
__global__ void detect_kernel(const u32* __restrict__ feat, int* __restrict__ flag) {
    int t = threadIdx.x;       // 64 threads
    float mx = 0.f;
#pragma unroll
    for (int i = 0; i < 4; ++i) {
        u32 u = feat[t * 4 + i];
        float a = fabsf(lo2f(u));
        float b = fabsf(hi2f(u));
        if (!(a < 1e30f)) a = 1e30f;   // NaN/inf -> strong f32 evidence
        if (!(b < 1e30f)) b = 1e30f;
        mx = fmaxf(mx, fmaxf(a, b));
    }
#pragma unroll
    for (int off = 32; off; off >>= 1) mx = fmaxf(mx, __shfl_xor(mx, off));
    if (t == 0) *flag = (mx > 1e6f) ? 1 : 0;
}

// ---------------------------------------------------------------------------
// K1: fused projections. q,k,v -> bf16 ws buffers; resid -> d_out directly.
// Block = 256 threads, 16 nodes. Thread: 8 output cols x 4 nodes.
// ---------------------------------------------------------------------------
template<int ISF32>
__device__ __forceinline__ void kloop(const void* Wbase, size_t eoff, int stride,
                                      const float (*sfeat)[INF], int ns, float acc[4][8]) {
    for (int i = 0; i < INF; ++i) {
        float wf[8];
        load8(Wbase, eoff, ISF32, wf);
        eoff += stride;
#pragma unroll
        for (int j = 0; j < 4; ++j) {
            float f = sfeat[ns + j][i];
#pragma unroll
            for (int l = 0; l < 8; ++l) acc[j][l] = fmaf(f, wf[l], acc[j][l]);
        }
    }
}

__global__ __launch_bounds__(256) void proj_kernel(
    const void* __restrict__ feat,
    const void* __restrict__ Wq, const void* __restrict__ bq,
    const void* __restrict__ Wk, const void* __restrict__ bk,
    const void* __restrict__ Wv, const void* __restrict__ bv,
    const void* __restrict__ Ws, const void* __restrict__ bs,
    u16* __restrict__ qb, u16* __restrict__ kb, u16* __restrict__ vb,
    void* __restrict__ outp, const int* __restrict__ flag)
{
    const int isf32 = *flag;
    __shared__ float sfeat[16][INF];   // 8 KB
    const int tid = threadIdx.x;
    const int n0 = blockIdx.x * 16;

    {
        float t[8];
        load8(feat, (size_t)n0 * INF + tid * 8, isf32, t);
        int r = tid >> 4, pb = (tid & 15) * 8;
#pragma unroll
        for (int l = 0; l < 8; ++l) sfeat[r][pb + l] = t[l];
    }
    __syncthreads();

    const int cg    = tid & 63;      // 64 col-groups x 8 cols = 512 outputs
    const int slice = tid >> 6;      // 4 node-slices x 4 nodes
    const int c0    = cg * 8;
    const int mat   = c0 >> 7;       // 0:q 1:k 2:v 3:self
    const int col   = c0 & 127;

    const void* Wbase = (mat == 0) ? Wq : (mat == 1) ? Wk : (mat == 2) ? Wv : Ws;
    const void* bbase = (mat == 0) ? bq : (mat == 1) ? bk : (mat == 2) ? bv : bs;
    size_t eoff; int stride;
    if (mat < 3) {
        int h = col >> 4, d0 = col & 15;
        eoff = (size_t)h * INF * HDIM + d0;   // W[h][i][d]
        stride = HDIM;
    } else {
        eoff = col;                            // Ws[i][c]
        stride = OUTF;
    }

    float acc[4][8];
#pragma unroll
    for (int j = 0; j < 4; ++j)
#pragma unroll
        for (int l = 0; l < 8; ++l) acc[j][l] = 0.f;

    const int ns = slice * 4;
    if (isf32) kloop<1>(Wbase, eoff, stride, sfeat, ns, acc);
    else       kloop<0>(Wbase, eoff, stride, sfeat, ns, acc);

    float bf[8];
    load8(bbase, (size_t)col, isf32, bf);   // bias offset == col for all 4 mats

#pragma unroll
    for (int j = 0; j < 4; ++j) {
        float v[8];
#pragma unroll
        for (int l = 0; l < 8; ++l) v[l] = acc[j][l] + bf[l];
        size_t ro = (size_t)(n0 + ns + j) * OUTF + col;
        if (mat < 3) {
            u16* dp = (mat == 0) ? qb : (mat == 1) ? kb : vb;
            *(uint4v*)(dp + ro) = pack8(v);
        } else {
            if (isf32) {
                float* op = (float*)outp + ro;
                *(float4*)op       = make_float4(v[0], v[1], v[2], v[3]);
                *(float4*)(op + 4) = make_float4(v[4], v[5], v[6], v[7]);
            } else {
                *(uint4v*)((u16*)outp + ro) = pack8(v);
            }
        }
    }
}

// ---------------------------------------------------------------------------
// CSR build: histogram -> single-block scan -> scatter (stores src id)
// ---------------------------------------------------------------------------
__global__ void count_kernel(const int* __restrict__ dst, int* __restrict__ counts, int E) {
    int e = blockIdx.x * blockDim.x + threadIdx.x;
    if (e < E) atomicAdd(&counts[dst[e]], 1);
}

__global__ __launch_bounds__(1024) void scan_kernel(const int* __restrict__ counts,
                                                    int* __restrict__ offsets,
                                                    int* __restrict__ cursor, int n) {
    __shared__ int wsum[16];
    __shared__ int carry_s;
    const int tid = threadIdx.x;
    const int lane = tid & 63;
    const int wid = tid >> 6;
    if (tid == 0) carry_s = 0;
    __syncthreads();
    for (int base = 0; base < n; base += 1024) {
        int idx = base + tid;
        int x = (idx < n) ? counts[idx] : 0;
        int v = x;
#pragma unroll
        for (int off = 1; off < 64; off <<= 1) {
            int y = __shfl_up(v, off);
            if (lane >= off) v += y;
        }
        if (lane == 63) wsum[wid] = v;
        __syncthreads();
        if (wid == 0 && lane < 16) {
            int w = wsum[lane];
#pragma unroll
            for (int off = 1; off < 16; off <<= 1) {
                int y = __shfl_up(w, off, 16);
                if (lane >= off) w += y;
            }
            wsum[lane] = w;
        }
        __syncthreads();
        int wave_excl = (wid == 0) ? 0 : wsum[wid - 1];
        int excl = carry_s + wave_excl + (v - x);
        if (idx < n) { offsets[idx] = excl; cursor[idx] = excl; }
        __syncthreads();
        if (tid == 0) carry_s += wsum[15];
        __syncthreads();
    }
    if (tid == 0) offsets[n] = carry_s;
}

__global__ void scatter_kernel(const int* __restrict__ dst, const int* __restrict__ src,
                               int* __restrict__ cursor, int* __restrict__ srcs, int E) {
    int e = blockIdx.x * blockDim.x + threadIdx.x;
    if (e < E) {
        int p = atomicAdd(&cursor[dst[e]], 1);
        srcs[p] = src[e];
    }
}

// ---------------------------------------------------------------------------
// K3: edge-score + softmax + aggregate + residual(RMW on out).
// 16 lanes own one (node, head); the 4 groups in a wave share one node ->
// uniform trip count. No segment-max pass: |score| <~ 12, f32 exp safe.
// ---------------------------------------------------------------------------
__global__ __launch_bounds__(256) void attn_kernel(
    const u16* __restrict__ qb, const u16* __restrict__ kb, const u16* __restrict__ vb,
    const int* __restrict__ offsets, const int* __restrict__ srcs,
    void* outp, const int* __restrict__ flag, int nGroups)
{
    const int g = blockIdx.x * 16 + (threadIdx.x >> 4);
    if (g >= nGroups) return;
    const int isf32 = *flag;
    const int lane = threadIdx.x & 15;
    const int n = g >> 3;
    const int h = g & 7;
    const int col = h * HDIM + lane;
    const size_t idx = (size_t)n * OUTF + col;

    const float qd = bf2f(qb[idx]);
    const int beg = offsets[n];
    const int end = offsets[n + 1];

    float den = 0.f, acc = 0.f;
    for (int p = beg; p < end; ++p) {
        int s = srcs[p];
        float kd = bf2f(kb[(size_t)s * OUTF + col]);
        float prod = qd * kd;
        prod += __shfl_xor(prod, 1, 16);
        prod += __shfl_xor(prod, 2, 16);
        prod += __shfl_xor(prod, 4, 16);
        prod += __shfl_xor(prod, 8, 16);
        float ex = __expf(prod * 0.25f);      // / sqrt(D=16)
        den += ex;
        acc = fmaf(ex, bf2f(vb[(size_t)s * OUTF + col]), acc);
    }
    float r = (den > 0.f) ? (acc / den) : 0.f;
    float resid = isf32 ? ((const float*)outp)[idx] : bf2f(((const u16*)outp)[idx]);
    float o = r + resid;
    if (isf32) ((float*)outp)[idx] = o;
    else       ((u16*)outp)[idx]   = f2bf(o);
}

// ---------------------------------------------------------------------------
extern "C" void kernel_launch(void* const* d_in, const int* in_sizes, int n_in,
                              void* d_out, int out_size, void* d_ws, size_t ws_size,
                              hipStream_t stream) {
    const void* feat = d_in[0];
    const int* src  = (const int*)d_in[1];
    const int* dst  = (const int*)d_in[2];
    const void* Wq = d_in[3]; const void* bq = d_in[4];
    const void* Wk = d_in[5]; const void* bk = d_in[6];
    const void* Wv = d_in[7]; const void* bv = d_in[8];
    const void* Ws = d_in[9]; const void* bs = d_in[10];

    const int N = in_sizes[0] / INF;   // 50000
    const int E = in_sizes[1];         // 800000

    // ws layout (~42.2 MB): q,k,v bf16 then int arrays
    u16* qb = (u16*)d_ws;
    u16* kb = qb + (size_t)N * OUTF;
    u16* vb = kb + (size_t)N * OUTF;
    int* counts  = (int*)(vb + (size_t)N * OUTF);
    int* offsets = counts + N;          // N+1
    int* cursor  = offsets + N + 1;
    int* srcs    = cursor + N;          // E
    int* flag    = srcs + E;

    hipMemsetAsync(counts, 0, (size_t)N * sizeof(int), stream);
    detect_kernel<<<1, 64, 0, stream>>>((const u32*)feat, flag);
    proj_kernel<<<(N + 15) / 16, 256, 0, stream>>>(feat, Wq, bq, Wk, bk, Wv, bv, Ws, bs,
                                                   qb, kb, vb, d_out, flag);
    count_kernel<<<(E + 255) / 256, 256, 0, stream>>>(dst, counts, E);
    scan_kernel<<<1, 1024, 0, stream>>>(counts, offsets, cursor, N);
    scatter_kernel<<<(E + 255) / 256, 256, 0, stream>>>(dst, src, cursor, srcs, E);
    attn_kernel<<<(N * NHEAD + 15) / 16, 256, 0, stream>>>(qb, kb, vb, offsets, srcs,
                                                           d_out, flag, N * NHEAD);
}

// Round 3
// 329.320 us; speedup vs baseline: 1.5281x; 1.5281x over previous
//
#include <hip/hip_runtime.h>
#include <hip/hip_bf16.h>

typedef unsigned short u16;
typedef unsigned int u32;
typedef __attribute__((ext_vector_type(4))) unsigned int uint4v;
typedef __bf16 bf16x8 __attribute__((ext_vector_type(8)));
typedef float f32x4 __attribute__((ext_vector_type(4)));

#define INF 128
#define OUTF 128
#define NHEAD 8
#define HDIM 16

__device__ __forceinline__ float lo2f(u32 u) { return __uint_as_float(u << 16); }
__device__ __forceinline__ float hi2f(u32 u) { return __uint_as_float(u & 0xffff0000u); }
__device__ __forceinline__ float bf2f(u16 b) { return __uint_as_float(((u32)b) << 16); }
__device__ __forceinline__ u16 f2bf(float x) {
    __hip_bfloat16 h = __float2bfloat16(x);   // RNE
    return *reinterpret_cast<u16*>(&h);
}

__device__ __forceinline__ void load8(const void* base, size_t eoff, int isf32, float o[8]) {
    if (isf32) {
        const float* p = (const float*)base + eoff;
        float4 a = *(const float4*)p;
        float4 b = *(const float4*)(p + 4);
        o[0] = a.x; o[1] = a.y; o[2] = a.z; o[3] = a.w;
        o[4] = b.x; o[5] = b.y; o[6] = b.z; o[7] = b.w;
    } else {
        uint4v u = *(const uint4v*)((const u16*)base + eoff);
        o[0] = lo2f(u.x); o[1] = hi2f(u.x);
        o[2] = lo2f(u.y); o[3] = hi2f(u.y);
        o[4] = lo2f(u.z); o[5] = hi2f(u.z);
        o[6] = lo2f(u.w); o[7] = hi2f(u.w);
    }
}

__device__ __forceinline__ uint4v pack8(const float v[8]) {
    uint4v u;
    u.x = (u32)f2bf(v[0]) | ((u32)f2bf(v[1]) << 16);
    u.y = (u32)f2bf(v[2]) | ((u32)f2bf(v[3]) << 16);
    u.z = (u32)f2bf(v[4]) | ((u32)f2bf(v[5]) << 16);
    u.w = (u32)f2bf(v[6]) | ((u32)f2bf(v[7]) << 16);
    return u;
}

__device__ __forceinline__ f32x4 mfma16(bf16x8 a, bf16x8 b, f32x4 c) {
    return __builtin_amdgcn_mfma_f32_16x16x32_bf16(a, b, c, 0, 0, 0);
}

// ---------------------------------------------------------------------------
// K0: dtype detector (unchanged — worked in round 2).
// ---------------------------------------------------------------------------
__global__ void detect_kernel(const u32* __restrict__ feat, int* __restrict__ flag) {
    int t = threadIdx.x;       // 64 threads
    float mx = 0.f;
#pragma unroll
    for (int i = 0; i < 4; ++i) {
        u32 u = feat[t * 4 + i];
        float a = fabsf(lo2f(u));
        float b = fabsf(hi2f(u));
        if (!(a < 1e30f)) a = 1e30f;
        if (!(b < 1e30f)) b = 1e30f;
        mx = fmaxf(mx, fmaxf(a, b));
    }
#pragma unroll
    for (int off = 32; off; off >>= 1) mx = fmaxf(mx, __shfl_xor(mx, off));
    if (t == 0) *flag = (mx > 1e6f) ? 1 : 0;
}

// ---------------------------------------------------------------------------
// K0b: weight prep. Wcat[col][k] bf16 (col: 0..127 q heads-major, 128..255 k,
// 256..383 v, 384..511 self), bcat[col] f32. B^T layout -> 16B B-frag loads.
// ---------------------------------------------------------------------------
__global__ void prep_kernel(const void* __restrict__ Wq, const void* __restrict__ bq,
                            const void* __restrict__ Wk, const void* __restrict__ bk,
                            const void* __restrict__ Wv, const void* __restrict__ bv,
                            const void* __restrict__ Ws, const void* __restrict__ bs,
                            u16* __restrict__ Wcat, float* __restrict__ bcat,
                            const int* __restrict__ flag) {
    const int isf32 = *flag;
    int col = blockIdx.x * 256 + threadIdx.x;
    if (col >= 512) return;
    int mat = col >> 7, c = col & 127;
    const void* W = (mat == 0) ? Wq : (mat == 1) ? Wk : (mat == 2) ? Wv : Ws;
    const void* bb = (mat == 0) ? bq : (mat == 1) ? bk : (mat == 2) ? bv : bs;
    size_t base; int stride;
    if (mat < 3) { int h = c >> 4, d = c & 15; base = (size_t)h * (INF * HDIM) + d; stride = HDIM; }
    else { base = c; stride = OUTF; }
    for (int i = 0; i < INF; ++i) {
        float w = isf32 ? ((const float*)W)[base + (size_t)i * stride]
                        : bf2f(((const u16*)W)[base + (size_t)i * stride]);
        Wcat[(size_t)col * INF + i] = f2bf(w);
    }
    bcat[col] = isf32 ? ((const float*)bb)[c] : bf2f(((const u16*)bb)[c]);
}

// ---------------------------------------------------------------------------
// K1: MFMA projections. 64 nodes/block, 256 thr (4 waves). Wave w owns
// col-tiles w*8..w*8+7 (16 cols each), all 4 row-tiles. K=128 in 4 steps.
// feat tile in LDS as bf16, XOR-swizzled (G4: 256B rows -> 16-way conflict
// without it). q,k,v -> bf16 ws; resid -> d_out.
// ---------------------------------------------------------------------------
__global__ __launch_bounds__(256) void proj_kernel(
    const void* __restrict__ feat, const u16* __restrict__ Wcat,
    const float* __restrict__ bcat,
    u16* __restrict__ qb, u16* __restrict__ kb, u16* __restrict__ vb,
    void* __restrict__ outp, const int* __restrict__ flag, int N)
{
    const int isf32 = *flag;
    __shared__ uint4v smem4[64 * 16];       // 64 rows x 256B = 16 KB
    char* sb = (char*)smem4;
    const int tid = threadIdx.x;
    const int n0 = blockIdx.x * 64;

    // stage 64 x 128 feat -> bf16 LDS (swizzled)
    {
        int row = tid >> 2;
        int k0 = (tid & 3) * 32;
        int rowg = n0 + row; if (rowg >= N) rowg = N - 1;   // clamp, stores guarded
        size_t goff = (size_t)rowg * INF + k0;
#pragma unroll
        for (int m = 0; m < 4; ++m) {
            float t[8];
            load8(feat, goff + m * 8, isf32, t);
            uint4v pk = pack8(t);
            int kbyte = 2 * (k0 + m * 8);
            int off = row * 256 + (kbyte ^ ((row & 7) << 4));
            *(uint4v*)(sb + off) = pk;
        }
    }
    __syncthreads();

    const int l = tid & 63, w = tid >> 6;
    const int lrow = l & 15, lk = l >> 4;

    // preload A-frags: af[rt][ks] = A[rt*16+lrow][ks*32 + lk*8 .. +7]
    bf16x8 af[4][4];
#pragma unroll
    for (int rt = 0; rt < 4; ++rt) {
        int row = rt * 16 + lrow;
#pragma unroll
        for (int ks = 0; ks < 4; ++ks) {
            int kbyte = ks * 64 + lk * 16;
            int off = row * 256 + (kbyte ^ ((row & 7) << 4));
            af[rt][ks] = *(const bf16x8*)(sb + off);
        }
    }

    for (int ct = 0; ct < 8; ++ct) {
        int ctg = w * 8 + ct;
        int colg = ctg * 16 + lrow;
        f32x4 acc[4] = {{0,0,0,0},{0,0,0,0},{0,0,0,0},{0,0,0,0}};
        const u16* wp = Wcat + (size_t)colg * INF + lk * 8;
#pragma unroll
        for (int ks = 0; ks < 4; ++ks) {
            bf16x8 bfr = *(const bf16x8*)(wp + ks * 32);
#pragma unroll
            for (int rt = 0; rt < 4; ++rt)
                acc[rt] = mfma16(af[rt][ks], bfr, acc[rt]);
        }
        float bias = bcat[colg];
        int mat = colg >> 7, c = colg & 127;
        u16* dp = (mat == 0) ? qb : (mat == 1) ? kb : vb;
#pragma unroll
        for (int rt = 0; rt < 4; ++rt) {
#pragma unroll
            for (int r = 0; r < 4; ++r) {
                int node = n0 + rt * 16 + lk * 4 + r;   // C/D: row=(lane>>4)*4+reg
                if (node < N) {
                    float v = acc[rt][r] + bias;
                    size_t o = (size_t)node * OUTF + c;
                    if (mat < 3)      dp[o] = f2bf(v);
                    else if (isf32)   ((float*)outp)[o] = v;
                    else              ((u16*)outp)[o]   = f2bf(v);
                }
            }
        }
    }
}

// ---------------------------------------------------------------------------
// CSR build: histogram -> single-block scan (8 elems/thread) -> scatter(src)
// ---------------------------------------------------------------------------
__global__ void count_kernel(const int* __restrict__ dst, int* __restrict__ counts, int E) {
    int e = blockIdx.x * blockDim.x + threadIdx.x;
    if (e < E) atomicAdd(&counts[dst[e]], 1);
}

__global__ __launch_bounds__(1024) void scan_kernel(const int* __restrict__ counts,
                                                    int* __restrict__ offsets,
                                                    int* __restrict__ cursor, int n) {
    __shared__ int wsum[16];
    __shared__ int carry_s;
    const int tid = threadIdx.x;
    const int lane = tid & 63;
    const int wid = tid >> 6;
    if (tid == 0) carry_s = 0;
    __syncthreads();
    for (int base = 0; base < n; base += 8192) {
        int i0 = base + tid * 8;
        int v[8]; int run = 0;
#pragma unroll
        for (int j = 0; j < 8; ++j) {
            int x = (i0 + j < n) ? counts[i0 + j] : 0;
            run += x; v[j] = run;                       // inclusive within chunk
        }
        int t = run, s = t;
#pragma unroll
        for (int off = 1; off < 64; off <<= 1) {
            int y = __shfl_up(s, off);
            if (lane >= off) s += y;
        }
        if (lane == 63) wsum[wid] = s;
        __syncthreads();
        if (wid == 0 && lane < 16) {
            int ws = wsum[lane];
#pragma unroll
            for (int off = 1; off < 16; off <<= 1) {
                int y = __shfl_up(ws, off, 16);
                if (lane >= off) ws += y;
            }
            wsum[lane] = ws;
        }
        __syncthreads();
        int wexcl = (wid == 0) ? 0 : wsum[wid - 1];
        int excl = carry_s + wexcl + (s - t);
#pragma unroll
        for (int j = 0; j < 8; ++j) {
            if (i0 + j < n) {
                int e = excl + (j ? v[j - 1] : 0);
                offsets[i0 + j] = e; cursor[i0 + j] = e;
            }
        }
        __syncthreads();
        if (tid == 0) carry_s += wsum[15];
        __syncthreads();
    }
    if (tid == 0) offsets[n] = carry_s;
}

__global__ void scatter_kernel(const int* __restrict__ dst, const int* __restrict__ src,
                               int* __restrict__ cursor, int* __restrict__ srcs, int E) {
    int e = blockIdx.x * blockDim.x + threadIdx.x;
    if (e < E) {
        int p = atomicAdd(&cursor[dst[e]], 1);
        srcs[p] = src[e];
    }
}

// ---------------------------------------------------------------------------
// K3: edge softmax + aggregate + residual RMW. 16 lanes per (node,head);
// a wave = 1 node x 4 adjacent heads -> 128B-coalesced k/v gathers and
// broadcast srcs loads. 4-edge unroll for memory-level parallelism.
// ---------------------------------------------------------------------------
__global__ __launch_bounds__(256) void attn_kernel(
    const u16* __restrict__ qb, const u16* __restrict__ kb, const u16* __restrict__ vb,
    const int* __restrict__ offsets, const int* __restrict__ srcs,
    void* outp, const int* __restrict__ flag, int nGroups)
{
    const int g = blockIdx.x * 16 + (threadIdx.x >> 4);
    if (g >= nGroups) return;
    const int isf32 = *flag;
    const int lane = threadIdx.x & 15;
    const int n = g >> 3;
    const int h = g & 7;
    const int col = h * HDIM + lane;
    const size_t idx = (size_t)n * OUTF + col;

    const float qd = bf2f(qb[idx]);
    const int beg = offsets[n];
    const int end = offsets[n + 1];

    float den = 0.f, acc = 0.f;
    int p = beg;
    for (; p + 4 <= end; p += 4) {
        int s0 = srcs[p + 0], s1 = srcs[p + 1], s2 = srcs[p + 2], s3 = srcs[p + 3];
        float k0 = bf2f(kb[(size_t)s0 * OUTF + col]);
        float k1 = bf2f(kb[(size_t)s1 * OUTF + col]);
        float k2 = bf2f(kb[(size_t)s2 * OUTF + col]);
        float k3 = bf2f(kb[(size_t)s3 * OUTF + col]);
        float v0 = bf2f(vb[(size_t)s0 * OUTF + col]);
        float v1 = bf2f(vb[(size_t)s1 * OUTF + col]);
        float v2 = bf2f(vb[(size_t)s2 * OUTF + col]);
        float v3 = bf2f(vb[(size_t)s3 * OUTF + col]);
        float p0 = qd * k0, p1 = qd * k1, p2 = qd * k2, p3 = qd * k3;
#pragma unroll
        for (int off = 1; off < 16; off <<= 1) {
            p0 += __shfl_xor(p0, off, 16);
            p1 += __shfl_xor(p1, off, 16);
            p2 += __shfl_xor(p2, off, 16);
            p3 += __shfl_xor(p3, off, 16);
        }
        float e0 = __expf(p0 * 0.25f), e1 = __expf(p1 * 0.25f);
        float e2 = __expf(p2 * 0.25f), e3 = __expf(p3 * 0.25f);
        den += (e0 + e1) + (e2 + e3);
        acc = fmaf(e0, v0, acc); acc = fmaf(e1, v1, acc);
        acc = fmaf(e2, v2, acc); acc = fmaf(e3, v3, acc);
    }
    for (; p < end; ++p) {
        int s = srcs[p];
        float kd = bf2f(kb[(size_t)s * OUTF + col]);
        float pr = qd * kd;
#pragma unroll
        for (int off = 1; off < 16; off <<= 1) pr += __shfl_xor(pr, off, 16);
        float e = __expf(pr * 0.25f);
        den += e;
        acc = fmaf(e, bf2f(vb[(size_t)s * OUTF + col]), acc);
    }
    float r = (den > 0.f) ? (acc / den) : 0.f;
    float resid = isf32 ? ((const float*)outp)[idx] : bf2f(((const u16*)outp)[idx]);
    float o = r + resid;
    if (isf32) ((float*)outp)[idx] = o;
    else       ((u16*)outp)[idx]   = f2bf(o);
}

// ---------------------------------------------------------------------------
extern "C" void kernel_launch(void* const* d_in, const int* in_sizes, int n_in,
                              void* d_out, int out_size, void* d_ws, size_t ws_size,
                              hipStream_t stream) {
    const void* feat = d_in[0];
    const int* src  = (const int*)d_in[1];
    const int* dst  = (const int*)d_in[2];
    const void* Wq = d_in[3]; const void* bq = d_in[4];
    const void* Wk = d_in[5]; const void* bk = d_in[6];
    const void* Wv = d_in[7]; const void* bv = d_in[8];
    const void* Ws = d_in[9]; const void* bs = d_in[10];

    const int N = in_sizes[0] / INF;   // 50000
    const int E = in_sizes[1];         // 800000

    // ws layout (16B-aligned chunks): q,k,v bf16; Wcat bf16; bcat f32; ints
    u16* qb = (u16*)d_ws;
    u16* kb = qb + (size_t)N * OUTF;                 // 12.8 MB each
    u16* vb = kb + (size_t)N * OUTF;
    u16* Wcat = vb + (size_t)N * OUTF;               // 512*128 bf16 = 128 KB
    float* bcat = (float*)(Wcat + 512 * INF);        // 2 KB
    int* counts  = (int*)(bcat + 512);
    int* offsets = counts + N;          // N+1
    int* cursor  = offsets + N + 1;
    int* srcs    = cursor + N;          // E
    int* flag    = srcs + E;

    hipMemsetAsync(counts, 0, (size_t)N * sizeof(int), stream);
    detect_kernel<<<1, 64, 0, stream>>>((const u32*)feat, flag);
    prep_kernel<<<2, 256, 0, stream>>>(Wq, bq, Wk, bk, Wv, bv, Ws, bs, Wcat, bcat, flag);
    proj_kernel<<<(N + 63) / 64, 256, 0, stream>>>(feat, Wcat, bcat, qb, kb, vb,
                                                   d_out, flag, N);
    count_kernel<<<(E + 255) / 256, 256, 0, stream>>>(dst, counts, E);
    scan_kernel<<<1, 1024, 0, stream>>>(counts, offsets, cursor, N);
    scatter_kernel<<<(E + 255) / 256, 256, 0, stream>>>(dst, src, cursor, srcs, E);
    attn_kernel<<<(N * NHEAD + 15) / 16, 256, 0, stream>>>(qb, kb, vb, offsets, srcs,
                                                           d_out, flag, N * NHEAD);
}

// Round 5
// 307.003 us; speedup vs baseline: 1.6391x; 1.0727x over previous
//
#include <hip/hip_runtime.h>
#include <hip/hip_bf16.h>

typedef unsigned short u16;
typedef unsigned int u32;
typedef __attribute__((ext_vector_type(4))) unsigned int uint4v;
typedef __bf16 bf16x8 __attribute__((ext_vector_type(8)));
typedef float f32x4 __attribute__((ext_vector_type(4)));

#define INF 128
#define OUTF 128
#define NHEAD 8
#define HDIM 16

__device__ __forceinline__ float lo2f(u32 u) { return __uint_as_float(u << 16); }
__device__ __forceinline__ float hi2f(u32 u) { return __uint_as_float(u & 0xffff0000u); }
__device__ __forceinline__ float bf2f(u16 b) { return __uint_as_float(((u32)b) << 16); }
__device__ __forceinline__ u16 f2bf(float x) {
    __hip_bfloat16 h = __float2bfloat16(x);   // RNE
    return *reinterpret_cast<u16*>(&h);
}
__device__ __forceinline__ float fast_exp2(float x) {
    return __builtin_amdgcn_exp2f(x);         // v_exp_f32: D = 2^S0
}

__device__ __forceinline__ void load8(const void* base, size_t eoff, int isf32, float o[8]) {
    if (isf32) {
        const float* p = (const float*)base + eoff;
        float4 a = *(const float4*)p;
        float4 b = *(const float4*)(p + 4);
        o[0] = a.x; o[1] = a.y; o[2] = a.z; o[3] = a.w;
        o[4] = b.x; o[5] = b.y; o[6] = b.z; o[7] = b.w;
    } else {
        uint4v u = *(const uint4v*)((const u16*)base + eoff);
        o[0] = lo2f(u.x); o[1] = hi2f(u.x);
        o[2] = lo2f(u.y); o[3] = hi2f(u.y);
        o[4] = lo2f(u.z); o[5] = hi2f(u.z);
        o[6] = lo2f(u.w); o[7] = hi2f(u.w);
    }
}

__device__ __forceinline__ uint4v pack8(const float v[8]) {
    uint4v u;
    u.x = (u32)f2bf(v[0]) | ((u32)f2bf(v[1]) << 16);
    u.y = (u32)f2bf(v[2]) | ((u32)f2bf(v[3]) << 16);
    u.z = (u32)f2bf(v[4]) | ((u32)f2bf(v[5]) << 16);
    u.w = (u32)f2bf(v[6]) | ((u32)f2bf(v[7]) << 16);
    return u;
}

__device__ __forceinline__ f32x4 mfma16(bf16x8 a, bf16x8 b, f32x4 c) {
    return __builtin_amdgcn_mfma_f32_16x16x32_bf16(a, b, c, 0, 0, 0);
}

// ---------------------------------------------------------------------------
// K0: weight prep with fused dtype-detect (both blocks compute the flag
// redundantly in shared mem; block 0 publishes it for later kernels).
// Wcat[col][k] bf16 (col: 0..127 q, 128..255 k, 256..383 v, 384..511 self).
// ---------------------------------------------------------------------------
__global__ __launch_bounds__(256) void prep_kernel(
    const u32* __restrict__ featw,
    const void* __restrict__ Wq, const void* __restrict__ bq,
    const void* __restrict__ Wk, const void* __restrict__ bk,
    const void* __restrict__ Wv, const void* __restrict__ bv,
    const void* __restrict__ Ws, const void* __restrict__ bs,
    u16* __restrict__ Wcat, float* __restrict__ bcat, int* __restrict__ flag)
{
    __shared__ int sflag;
    const int tid = threadIdx.x;
    if (tid < 64) {
        float mx = 0.f;
#pragma unroll
        for (int i = 0; i < 4; ++i) {
            u32 u = featw[tid * 4 + i];
            float a = fabsf(lo2f(u));
            float b = fabsf(hi2f(u));
            if (!(a < 1e30f)) a = 1e30f;
            if (!(b < 1e30f)) b = 1e30f;
            mx = fmaxf(mx, fmaxf(a, b));
        }
#pragma unroll
        for (int off = 32; off; off >>= 1) mx = fmaxf(mx, __shfl_xor(mx, off));
        if (tid == 0) sflag = (mx > 1e6f) ? 1 : 0;
    }
    __syncthreads();
    const int isf32 = sflag;
    if (blockIdx.x == 0 && tid == 0) *flag = isf32;

    int col = blockIdx.x * 256 + tid;
    if (col >= 512) return;
    int mat = col >> 7, c = col & 127;
    const void* W = (mat == 0) ? Wq : (mat == 1) ? Wk : (mat == 2) ? Wv : Ws;
    const void* bb = (mat == 0) ? bq : (mat == 1) ? bk : (mat == 2) ? bv : bs;
    size_t base; int stride;
    if (mat < 3) { int h = c >> 4, d = c & 15; base = (size_t)h * (INF * HDIM) + d; stride = HDIM; }
    else { base = c; stride = OUTF; }
    for (int i = 0; i < INF; ++i) {
        float w = isf32 ? ((const float*)W)[base + (size_t)i * stride]
                        : bf2f(((const u16*)W)[base + (size_t)i * stride]);
        Wcat[(size_t)col * INF + i] = f2bf(w);
    }
    bcat[col] = isf32 ? ((const float*)bb)[c] : bf2f(((const u16*)bb)[c]);
}

// ---------------------------------------------------------------------------
// K1: MFMA projections. 64 nodes/block, 4 waves; wave owns 8 col-tiles.
// B-fragment loads double-buffered across the ct loop. q,k,v -> bf16 ws;
// resid -> d_out.
// ---------------------------------------------------------------------------
__global__ __launch_bounds__(256) void proj_kernel(
    const void* __restrict__ feat, const u16* __restrict__ Wcat,
    const float* __restrict__ bcat,
    u16* __restrict__ qb, u16* __restrict__ kb, u16* __restrict__ vb,
    void* __restrict__ outp, const int* __restrict__ flag, int N)
{
    const int isf32 = *flag;
    __shared__ uint4v smem4[64 * 16];       // 64 rows x 256B = 16 KB
    char* sb = (char*)smem4;
    const int tid = threadIdx.x;
    const int n0 = blockIdx.x * 64;

    // stage 64 x 128 feat -> bf16 LDS (XOR-swizzled: 256B rows)
    {
        int row = tid >> 2;
        int k0 = (tid & 3) * 32;
        int rowg = n0 + row; if (rowg >= N) rowg = N - 1;
        size_t goff = (size_t)rowg * INF + k0;
#pragma unroll
        for (int m = 0; m < 4; ++m) {
            float t[8];
            load8(feat, goff + m * 8, isf32, t);
            uint4v pk = pack8(t);
            int kbyte = 2 * (k0 + m * 8);
            int off = row * 256 + (kbyte ^ ((row & 7) << 4));
            *(uint4v*)(sb + off) = pk;
        }
    }
    __syncthreads();

    const int l = tid & 63, w = tid >> 6;
    const int lrow = l & 15, lk = l >> 4;

    bf16x8 af[4][4];
#pragma unroll
    for (int rt = 0; rt < 4; ++rt) {
        int row = rt * 16 + lrow;
#pragma unroll
        for (int ks = 0; ks < 4; ++ks) {
            int kbyte = ks * 64 + lk * 16;
            int off = row * 256 + (kbyte ^ ((row & 7) << 4));
            af[rt][ks] = *(const bf16x8*)(sb + off);
        }
    }

    // per-wave weight base: colg(ct) = (w*8+ct)*16 + lrow
    const u16* wb = Wcat + (size_t)(w * 128 + lrow) * INF + lk * 8;
    float biases[8];
#pragma unroll
    for (int ct = 0; ct < 8; ++ct) biases[ct] = bcat[(w * 8 + ct) * 16 + lrow];

    bf16x8 bufA[4], bufB[4];
#pragma unroll
    for (int ks = 0; ks < 4; ++ks) bufA[ks] = *(const bf16x8*)(wb + ks * 32);

#pragma unroll
    for (int ct = 0; ct < 8; ++ct) {
        bf16x8* cur = (ct & 1) ? bufB : bufA;   // static after unroll
        bf16x8* nxt = (ct & 1) ? bufA : bufB;
        if (ct < 7) {
#pragma unroll
            for (int ks = 0; ks < 4; ++ks)
                nxt[ks] = *(const bf16x8*)(wb + (size_t)(ct + 1) * 16 * INF + ks * 32);
        }
        f32x4 acc[4] = {{0,0,0,0},{0,0,0,0},{0,0,0,0},{0,0,0,0}};
#pragma unroll
        for (int ks = 0; ks < 4; ++ks)
#pragma unroll
            for (int rt = 0; rt < 4; ++rt)
                acc[rt] = mfma16(af[rt][ks], cur[ks], acc[rt]);

        int colg = (w * 8 + ct) * 16 + lrow;
        float bias = biases[ct];
        int mat = colg >> 7, c = colg & 127;
        u16* dp = (mat == 0) ? qb : (mat == 1) ? kb : vb;
#pragma unroll
        for (int rt = 0; rt < 4; ++rt) {
#pragma unroll
            for (int r = 0; r < 4; ++r) {
                int node = n0 + rt * 16 + lk * 4 + r;   // C/D: row=(lane>>4)*4+reg
                if (node < N) {
                    float v = acc[rt][r] + bias;
                    size_t o = (size_t)node * OUTF + c;
                    if (mat < 3)      dp[o] = f2bf(v);
                    else if (isf32)   ((float*)outp)[o] = v;
                    else              ((u16*)outp)[o]   = f2bf(v);
                }
            }
        }
    }
}

// ---------------------------------------------------------------------------
// CSR build: histogram -> single-block scan (8/thread) -> scatter(src)
// ---------------------------------------------------------------------------
__global__ void count_kernel(const int* __restrict__ dst, int* __restrict__ counts, int E) {
    int e = blockIdx.x * blockDim.x + threadIdx.x;
    if (e < E) atomicAdd(&counts[dst[e]], 1);
}

__global__ __launch_bounds__(1024) void scan_kernel(const int* __restrict__ counts,
                                                    int* __restrict__ offsets,
                                                    int* __restrict__ cursor, int n) {
    __shared__ int wsum[16];
    __shared__ int carry_s;
    const int tid = threadIdx.x;
    const int lane = tid & 63;
    const int wid = tid >> 6;
    if (tid == 0) carry_s = 0;
    __syncthreads();
    for (int base = 0; base < n; base += 8192) {
        int i0 = base + tid * 8;
        int v[8]; int run = 0;
#pragma unroll
        for (int j = 0; j < 8; ++j) {
            int x = (i0 + j < n) ? counts[i0 + j] : 0;
            run += x; v[j] = run;
        }
        int t = run, s = t;
#pragma unroll
        for (int off = 1; off < 64; off <<= 1) {
            int y = __shfl_up(s, off);
            if (lane >= off) s += y;
        }
        if (lane == 63) wsum[wid] = s;
        __syncthreads();
        if (wid == 0 && lane < 16) {
            int ws = wsum[lane];
#pragma unroll
            for (int off = 1; off < 16; off <<= 1) {
                int y = __shfl_up(ws, off, 16);
                if (lane >= off) ws += y;
            }
            wsum[lane] = ws;
        }
        __syncthreads();
        int wexcl = (wid == 0) ? 0 : wsum[wid - 1];
        int excl = carry_s + wexcl + (s - t);
#pragma unroll
        for (int j = 0; j < 8; ++j) {
            if (i0 + j < n) {
                int e = excl + (j ? v[j - 1] : 0);
                offsets[i0 + j] = e; cursor[i0 + j] = e;
            }
        }
        __syncthreads();
        if (tid == 0) carry_s += wsum[15];
        __syncthreads();
    }
    if (tid == 0) offsets[n] = carry_s;
}

__global__ void scatter_kernel(const int* __restrict__ dst, const int* __restrict__ src,
                               int* __restrict__ cursor, int* __restrict__ srcs, int E) {
    int e = blockIdx.x * blockDim.x + threadIdx.x;
    if (e < E) {
        int p = atomicAdd(&cursor[dst[e]], 1);
        srcs[p] = src[e];
    }
}

// ---------------------------------------------------------------------------
// K3: edge softmax + aggregate + residual RMW.
// ONE WAVE PER NODE, all 8 heads: lane owns cols {2*lane, 2*lane+1} (one
// dword of bf16x2). Per edge: one 256B k-gather + one 256B v-gather
// (wave-contiguous), 2-wide fma dot, 3-level shfl reduce within 8-lane head
// groups, single exp per edge covering all heads. 4-edge unroll for MLP.
// ---------------------------------------------------------------------------
__global__ __launch_bounds__(256) void attn_kernel(
    const u16* __restrict__ qb, const u16* __restrict__ kb, const u16* __restrict__ vb,
    const int* __restrict__ offsets, const int* __restrict__ srcs,
    void* __restrict__ outp, const int* __restrict__ flag, int N)
{
    const int n = blockIdx.x * 4 + (threadIdx.x >> 6);
    if (n >= N) return;
    const int isf32 = *flag;
    const int lane = threadIdx.x & 63;

    const u32* __restrict__ kdw = (const u32*)kb;
    const u32* __restrict__ vdw = (const u32*)vb;

    const u32 qu = ((const u32*)qb)[(size_t)n * 64 + lane];
    const float q0 = lo2f(qu), q1 = hi2f(qu);
    const float C = 0.36067376022224085f;   // 0.25 * log2(e)

    const int beg = offsets[n];
    const int end = offsets[n + 1];

    float den = 0.f, a0 = 0.f, a1 = 0.f;
    int p = beg;
    for (; p + 4 <= end; p += 4) {
        int s0 = srcs[p + 0], s1 = srcs[p + 1], s2 = srcs[p + 2], s3 = srcs[p + 3];
        u32 ku0 = kdw[(size_t)s0 * 64 + lane], vu0 = vdw[(size_t)s0 * 64 + lane];
        u32 ku1 = kdw[(size_t)s1 * 64 + lane], vu1 = vdw[(size_t)s1 * 64 + lane];
        u32 ku2 = kdw[(size_t)s2 * 64 + lane], vu2 = vdw[(size_t)s2 * 64 + lane];
        u32 ku3 = kdw[(size_t)s3 * 64 + lane], vu3 = vdw[(size_t)s3 * 64 + lane];
        float p0 = fmaf(hi2f(ku0), q1, lo2f(ku0) * q0);
        float p1 = fmaf(hi2f(ku1), q1, lo2f(ku1) * q0);
        float p2 = fmaf(hi2f(ku2), q1, lo2f(ku2) * q0);
        float p3 = fmaf(hi2f(ku3), q1, lo2f(ku3) * q0);
        p0 += __shfl_xor(p0, 1); p1 += __shfl_xor(p1, 1);
        p2 += __shfl_xor(p2, 1); p3 += __shfl_xor(p3, 1);
        p0 += __shfl_xor(p0, 2); p1 += __shfl_xor(p1, 2);
        p2 += __shfl_xor(p2, 2); p3 += __shfl_xor(p3, 2);
        p0 += __shfl_xor(p0, 4); p1 += __shfl_xor(p1, 4);
        p2 += __shfl_xor(p2, 4); p3 += __shfl_xor(p3, 4);
        float e0 = fast_exp2(p0 * C), e1 = fast_exp2(p1 * C);
        float e2 = fast_exp2(p2 * C), e3 = fast_exp2(p3 * C);
        den += (e0 + e1) + (e2 + e3);
        a0 = fmaf(e0, lo2f(vu0), a0); a1 = fmaf(e0, hi2f(vu0), a1);
        a0 = fmaf(e1, lo2f(vu1), a0); a1 = fmaf(e1, hi2f(vu1), a1);
        a0 = fmaf(e2, lo2f(vu2), a0); a1 = fmaf(e2, hi2f(vu2), a1);
        a0 = fmaf(e3, lo2f(vu3), a0); a1 = fmaf(e3, hi2f(vu3), a1);
    }
    for (; p < end; ++p) {
        int s = srcs[p];
        u32 ku = kdw[(size_t)s * 64 + lane], vu = vdw[(size_t)s * 64 + lane];
        float pr = fmaf(hi2f(ku), q1, lo2f(ku) * q0);
        pr += __shfl_xor(pr, 1); pr += __shfl_xor(pr, 2); pr += __shfl_xor(pr, 4);
        float e = fast_exp2(pr * C);
        den += e;
        a0 = fmaf(e, lo2f(vu), a0); a1 = fmaf(e, hi2f(vu), a1);
    }
    float inv = (den > 0.f) ? (1.0f / den) : 0.f;
    float r0 = a0 * inv, r1 = a1 * inv;
    if (isf32) {
        float2* op = (float2*)outp + (size_t)n * 64 + lane;
        float2 o = *op; o.x += r0; o.y += r1; *op = o;
    } else {
        u32* op = (u32*)outp + (size_t)n * 64 + lane;
        u32 ou = *op;
        u32 pk = (u32)f2bf(lo2f(ou) + r0) | ((u32)f2bf(hi2f(ou) + r1) << 16);
        *op = pk;
    }
}

// ---------------------------------------------------------------------------
extern "C" void kernel_launch(void* const* d_in, const int* in_sizes, int n_in,
                              void* d_out, int out_size, void* d_ws, size_t ws_size,
                              hipStream_t stream) {
    const void* feat = d_in[0];
    const int* src  = (const int*)d_in[1];
    const int* dst  = (const int*)d_in[2];
    const void* Wq = d_in[3]; const void* bq = d_in[4];
    const void* Wk = d_in[5]; const void* bk = d_in[6];
    const void* Wv = d_in[7]; const void* bv = d_in[8];
    const void* Ws = d_in[9]; const void* bs = d_in[10];

    const int N = in_sizes[0] / INF;   // 50000
    const int E = in_sizes[1];         // 800000

    u16* qb = (u16*)d_ws;
    u16* kb = qb + (size_t)N * OUTF;
    u16* vb = kb + (size_t)N * OUTF;
    u16* Wcat = vb + (size_t)N * OUTF;               // 512*128 bf16 = 128 KB
    float* bcat = (float*)(Wcat + 512 * INF);        // 2 KB
    int* counts  = (int*)(bcat + 512);
    int* offsets = counts + N;          // N+1
    int* cursor  = offsets + N + 1;
    int* srcs    = cursor + N;          // E
    int* flag    = srcs + E;

    (void)hipMemsetAsync(counts, 0, (size_t)N * sizeof(int), stream);
    prep_kernel<<<2, 256, 0, stream>>>((const u32*)feat, Wq, bq, Wk, bk, Wv, bv, Ws, bs,
                                       Wcat, bcat, flag);
    proj_kernel<<<(N + 63) / 64, 256, 0, stream>>>(feat, Wcat, bcat, qb, kb, vb,
                                                   d_out, flag, N);
    count_kernel<<<(E + 255) / 256, 256, 0, stream>>>(dst, counts, E);
    scan_kernel<<<1, 1024, 0, stream>>>(counts, offsets, cursor, N);
    scatter_kernel<<<(E + 255) / 256, 256, 0, stream>>>(dst, src, cursor, srcs, E);
    attn_kernel<<<(N + 3) / 4, 256, 0, stream>>>(qb, kb, vb, offsets, srcs,
                                                 d_out, flag, N);
}

// Round 6
// 247.169 us; speedup vs baseline: 2.0359x; 1.2421x over previous
//
#include <hip/hip_runtime.h>
#include <hip/hip_bf16.h>

typedef unsigned short u16;
typedef unsigned int u32;
typedef __attribute__((ext_vector_type(4))) unsigned int uint4v;
typedef __bf16 bf16x8 __attribute__((ext_vector_type(8)));
typedef float f32x4 __attribute__((ext_vector_type(4)));

#define INF 128
#define OUTF 128
#define NHEAD 8
#define HDIM 16

__device__ __forceinline__ float lo2f(u32 u) { return __uint_as_float(u << 16); }
__device__ __forceinline__ float hi2f(u32 u) { return __uint_as_float(u & 0xffff0000u); }
__device__ __forceinline__ float bf2f(u16 b) { return __uint_as_float(((u32)b) << 16); }
__device__ __forceinline__ u16 f2bf(float x) {
    __hip_bfloat16 h = __float2bfloat16(x);   // RNE
    return *reinterpret_cast<u16*>(&h);
}
__device__ __forceinline__ float fast_exp2(float x) {
    return __builtin_amdgcn_exp2f(x);         // v_exp_f32: D = 2^S0
}

__device__ __forceinline__ void load8(const void* base, size_t eoff, int isf32, float o[8]) {
    if (isf32) {
        const float* p = (const float*)base + eoff;
        float4 a = *(const float4*)p;
        float4 b = *(const float4*)(p + 4);
        o[0] = a.x; o[1] = a.y; o[2] = a.z; o[3] = a.w;
        o[4] = b.x; o[5] = b.y; o[6] = b.z; o[7] = b.w;
    } else {
        uint4v u = *(const uint4v*)((const u16*)base + eoff);
        o[0] = lo2f(u.x); o[1] = hi2f(u.x);
        o[2] = lo2f(u.y); o[3] = hi2f(u.y);
        o[4] = lo2f(u.z); o[5] = hi2f(u.z);
        o[6] = lo2f(u.w); o[7] = hi2f(u.w);
    }
}

__device__ __forceinline__ uint4v pack8(const float v[8]) {
    uint4v u;
    u.x = (u32)f2bf(v[0]) | ((u32)f2bf(v[1]) << 16);
    u.y = (u32)f2bf(v[2]) | ((u32)f2bf(v[3]) << 16);
    u.z = (u32)f2bf(v[4]) | ((u32)f2bf(v[5]) << 16);
    u.w = (u32)f2bf(v[6]) | ((u32)f2bf(v[7]) << 16);
    return u;
}

__device__ __forceinline__ f32x4 mfma16(bf16x8 a, bf16x8 b, f32x4 c) {
    return __builtin_amdgcn_mfma_f32_16x16x32_bf16(a, b, c, 0, 0, 0);
}

// ---------------------------------------------------------------------------
// K0: weight prep with fused dtype-detect (both blocks compute the flag
// redundantly in shared mem; block 0 publishes it for later kernels).
// Wcat[col][k] bf16 (col: 0..127 q, 128..255 k, 256..383 v, 384..511 self).
// ---------------------------------------------------------------------------
__global__ __launch_bounds__(256) void prep_kernel(
    const u32* __restrict__ featw,
    const void* __restrict__ Wq, const void* __restrict__ bq,
    const void* __restrict__ Wk, const void* __restrict__ bk,
    const void* __restrict__ Wv, const void* __restrict__ bv,
    const void* __restrict__ Ws, const void* __restrict__ bs,
    u16* __restrict__ Wcat, float* __restrict__ bcat, int* __restrict__ flag)
{
    __shared__ int sflag;
    const int tid = threadIdx.x;
    if (tid < 64) {
        float mx = 0.f;
#pragma unroll
        for (int i = 0; i < 4; ++i) {
            u32 u = featw[tid * 4 + i];
            float a = fabsf(lo2f(u));
            float b = fabsf(hi2f(u));
            if (!(a < 1e30f)) a = 1e30f;
            if (!(b < 1e30f)) b = 1e30f;
            mx = fmaxf(mx, fmaxf(a, b));
        }
#pragma unroll
        for (int off = 32; off; off >>= 1) mx = fmaxf(mx, __shfl_xor(mx, off));
        if (tid == 0) sflag = (mx > 1e6f) ? 1 : 0;
    }
    __syncthreads();
    const int isf32 = sflag;
    if (blockIdx.x == 0 && tid == 0) *flag = isf32;

    int col = blockIdx.x * 256 + tid;
    if (col >= 512) return;
    int mat = col >> 7, c = col & 127;
    const void* W = (mat == 0) ? Wq : (mat == 1) ? Wk : (mat == 2) ? Wv : Ws;
    const void* bb = (mat == 0) ? bq : (mat == 1) ? bk : (mat == 2) ? bv : bs;
    size_t base; int stride;
    if (mat < 3) { int h = c >> 4, d = c & 15; base = (size_t)h * (INF * HDIM) + d; stride = HDIM; }
    else { base = c; stride = OUTF; }
    for (int i = 0; i < INF; ++i) {
        float w = isf32 ? ((const float*)W)[base + (size_t)i * stride]
                        : bf2f(((const u16*)W)[base + (size_t)i * stride]);
        Wcat[(size_t)col * INF + i] = f2bf(w);
    }
    bcat[col] = isf32 ? ((const float*)bb)[c] : bf2f(((const u16*)bb)[c]);
}

// ---------------------------------------------------------------------------
// K1: MFMA projections. 64 nodes/block, 4 waves; wave owns 8 col-tiles.
// B-fragment loads double-buffered across the ct loop. q,k,v -> bf16 ws;
// resid -> d_out.
// ---------------------------------------------------------------------------
__global__ __launch_bounds__(256) void proj_kernel(
    const void* __restrict__ feat, const u16* __restrict__ Wcat,
    const float* __restrict__ bcat,
    u16* __restrict__ qb, u16* __restrict__ kb, u16* __restrict__ vb,
    void* __restrict__ outp, const int* __restrict__ flag, int N)
{
    const int isf32 = *flag;
    __shared__ uint4v smem4[64 * 16];       // 64 rows x 256B = 16 KB
    char* sb = (char*)smem4;
    const int tid = threadIdx.x;
    const int n0 = blockIdx.x * 64;

    // stage 64 x 128 feat -> bf16 LDS (XOR-swizzled: 256B rows)
    {
        int row = tid >> 2;
        int k0 = (tid & 3) * 32;
        int rowg = n0 + row; if (rowg >= N) rowg = N - 1;
        size_t goff = (size_t)rowg * INF + k0;
#pragma unroll
        for (int m = 0; m < 4; ++m) {
            float t[8];
            load8(feat, goff + m * 8, isf32, t);
            uint4v pk = pack8(t);
            int kbyte = 2 * (k0 + m * 8);
            int off = row * 256 + (kbyte ^ ((row & 7) << 4));
            *(uint4v*)(sb + off) = pk;
        }
    }
    __syncthreads();

    const int l = tid & 63, w = tid >> 6;
    const int lrow = l & 15, lk = l >> 4;

    bf16x8 af[4][4];
#pragma unroll
    for (int rt = 0; rt < 4; ++rt) {
        int row = rt * 16 + lrow;
#pragma unroll
        for (int ks = 0; ks < 4; ++ks) {
            int kbyte = ks * 64 + lk * 16;
            int off = row * 256 + (kbyte ^ ((row & 7) << 4));
            af[rt][ks] = *(const bf16x8*)(sb + off);
        }
    }

    // per-wave weight base: colg(ct) = (w*8+ct)*16 + lrow
    const u16* wb = Wcat + (size_t)(w * 128 + lrow) * INF + lk * 8;
    float biases[8];
#pragma unroll
    for (int ct = 0; ct < 8; ++ct) biases[ct] = bcat[(w * 8 + ct) * 16 + lrow];

    bf16x8 bufA[4], bufB[4];
#pragma unroll
    for (int ks = 0; ks < 4; ++ks) bufA[ks] = *(const bf16x8*)(wb + ks * 32);

#pragma unroll
    for (int ct = 0; ct < 8; ++ct) {
        bf16x8* cur = (ct & 1) ? bufB : bufA;   // static after unroll
        bf16x8* nxt = (ct & 1) ? bufA : bufB;
        if (ct < 7) {
#pragma unroll
            for (int ks = 0; ks < 4; ++ks)
                nxt[ks] = *(const bf16x8*)(wb + (size_t)(ct + 1) * 16 * INF + ks * 32);
        }
        f32x4 acc[4] = {{0,0,0,0},{0,0,0,0},{0,0,0,0},{0,0,0,0}};
#pragma unroll
        for (int ks = 0; ks < 4; ++ks)
#pragma unroll
            for (int rt = 0; rt < 4; ++rt)
                acc[rt] = mfma16(af[rt][ks], cur[ks], acc[rt]);

        int colg = (w * 8 + ct) * 16 + lrow;
        float bias = biases[ct];
        int mat = colg >> 7, c = colg & 127;
        u16* dp = (mat == 0) ? qb : (mat == 1) ? kb : vb;
#pragma unroll
        for (int rt = 0; rt < 4; ++rt) {
#pragma unroll
            for (int r = 0; r < 4; ++r) {
                int node = n0 + rt * 16 + lk * 4 + r;   // C/D: row=(lane>>4)*4+reg
                if (node < N) {
                    float v = acc[rt][r] + bias;
                    size_t o = (size_t)node * OUTF + c;
                    if (mat < 3)      dp[o] = f2bf(v);
                    else if (isf32)   ((float*)outp)[o] = v;
                    else              ((u16*)outp)[o]   = f2bf(v);
                }
            }
        }
    }
}

// ---------------------------------------------------------------------------
// CSR build: histogram -> wave-aggregated atomic segment allocation ->
// scatter(src). No device-wide scan: segments just need to be disjoint in
// [0,E); attn reads start[n] / start[n]+counts[n] directly.
// ---------------------------------------------------------------------------
__global__ void count_kernel(const int* __restrict__ dst, int* __restrict__ counts, int E) {
    int e = blockIdx.x * blockDim.x + threadIdx.x;
    if (e < E) atomicAdd(&counts[dst[e]], 1);
}

__global__ __launch_bounds__(256) void alloc_kernel(const int* __restrict__ counts,
                                                    int* __restrict__ start,
                                                    int* __restrict__ cursor,
                                                    int* __restrict__ counter, int n) {
    const int i = blockIdx.x * 256 + threadIdx.x;
    const int lane = threadIdx.x & 63;
    int cnt = (i < n) ? counts[i] : 0;
    int v = cnt;
#pragma unroll
    for (int off = 1; off < 64; off <<= 1) {
        int y = __shfl_up(v, off);
        if (lane >= off) v += y;
    }
    int base = 0;
    if (lane == 63) base = atomicAdd(counter, v);   // v@63 == wave total
    base = __shfl(base, 63);
    int s = base + v - cnt;
    if (i < n) { start[i] = s; cursor[i] = s; }
}

__global__ void scatter_kernel(const int* __restrict__ dst, const int* __restrict__ src,
                               int* __restrict__ cursor, int* __restrict__ srcs, int E) {
    int e = blockIdx.x * blockDim.x + threadIdx.x;
    if (e < E) {
        int p = atomicAdd(&cursor[dst[e]], 1);
        srcs[p] = src[e];
    }
}

// ---------------------------------------------------------------------------
// K3: edge softmax + aggregate + residual RMW.
// ONE WAVE PER NODE, all 8 heads: lane owns cols {2*lane, 2*lane+1} (one
// dword of bf16x2). Per edge: one 256B k-gather + one 256B v-gather
// (wave-contiguous), 2-wide fma dot, 3-level shfl reduce within 8-lane head
// groups, single exp per edge covering all heads. 4-edge unroll for MLP.
// ---------------------------------------------------------------------------
__global__ __launch_bounds__(256) void attn_kernel(
    const u16* __restrict__ qb, const u16* __restrict__ kb, const u16* __restrict__ vb,
    const int* __restrict__ start, const int* __restrict__ counts,
    const int* __restrict__ srcs,
    void* __restrict__ outp, const int* __restrict__ flag, int N)
{
    const int n = blockIdx.x * 4 + (threadIdx.x >> 6);
    if (n >= N) return;
    const int isf32 = *flag;
    const int lane = threadIdx.x & 63;

    const u32* __restrict__ kdw = (const u32*)kb;
    const u32* __restrict__ vdw = (const u32*)vb;

    const u32 qu = ((const u32*)qb)[(size_t)n * 64 + lane];
    const float q0 = lo2f(qu), q1 = hi2f(qu);
    const float C = 0.36067376022224085f;   // 0.25 * log2(e)

    const int beg = start[n];
    const int end = beg + counts[n];

    float den = 0.f, a0 = 0.f, a1 = 0.f;
    int p = beg;
    for (; p + 4 <= end; p += 4) {
        int s0 = srcs[p + 0], s1 = srcs[p + 1], s2 = srcs[p + 2], s3 = srcs[p + 3];
        u32 ku0 = kdw[(size_t)s0 * 64 + lane], vu0 = vdw[(size_t)s0 * 64 + lane];
        u32 ku1 = kdw[(size_t)s1 * 64 + lane], vu1 = vdw[(size_t)s1 * 64 + lane];
        u32 ku2 = kdw[(size_t)s2 * 64 + lane], vu2 = vdw[(size_t)s2 * 64 + lane];
        u32 ku3 = kdw[(size_t)s3 * 64 + lane], vu3 = vdw[(size_t)s3 * 64 + lane];
        float p0 = fmaf(hi2f(ku0), q1, lo2f(ku0) * q0);
        float p1 = fmaf(hi2f(ku1), q1, lo2f(ku1) * q0);
        float p2 = fmaf(hi2f(ku2), q1, lo2f(ku2) * q0);
        float p3 = fmaf(hi2f(ku3), q1, lo2f(ku3) * q0);
        p0 += __shfl_xor(p0, 1); p1 += __shfl_xor(p1, 1);
        p2 += __shfl_xor(p2, 1); p3 += __shfl_xor(p3, 1);
        p0 += __shfl_xor(p0, 2); p1 += __shfl_xor(p1, 2);
        p2 += __shfl_xor(p2, 2); p3 += __shfl_xor(p3, 2);
        p0 += __shfl_xor(p0, 4); p1 += __shfl_xor(p1, 4);
        p2 += __shfl_xor(p2, 4); p3 += __shfl_xor(p3, 4);
        float e0 = fast_exp2(p0 * C), e1 = fast_exp2(p1 * C);
        float e2 = fast_exp2(p2 * C), e3 = fast_exp2(p3 * C);
        den += (e0 + e1) + (e2 + e3);
        a0 = fmaf(e0, lo2f(vu0), a0); a1 = fmaf(e0, hi2f(vu0), a1);
        a0 = fmaf(e1, lo2f(vu1), a0); a1 = fmaf(e1, hi2f(vu1), a1);
        a0 = fmaf(e2, lo2f(vu2), a0); a1 = fmaf(e2, hi2f(vu2), a1);
        a0 = fmaf(e3, lo2f(vu3), a0); a1 = fmaf(e3, hi2f(vu3), a1);
    }
    for (; p < end; ++p) {
        int s = srcs[p];
        u32 ku = kdw[(size_t)s * 64 + lane], vu = vdw[(size_t)s * 64 + lane];
        float pr = fmaf(hi2f(ku), q1, lo2f(ku) * q0);
        pr += __shfl_xor(pr, 1); pr += __shfl_xor(pr, 2); pr += __shfl_xor(pr, 4);
        float e = fast_exp2(pr * C);
        den += e;
        a0 = fmaf(e, lo2f(vu), a0); a1 = fmaf(e, hi2f(vu), a1);
    }
    float inv = (den > 0.f) ? (1.0f / den) : 0.f;
    float r0 = a0 * inv, r1 = a1 * inv;
    if (isf32) {
        float2* op = (float2*)outp + (size_t)n * 64 + lane;
        float2 o = *op; o.x += r0; o.y += r1; *op = o;
    } else {
        u32* op = (u32*)outp + (size_t)n * 64 + lane;
        u32 ou = *op;
        u32 pk = (u32)f2bf(lo2f(ou) + r0) | ((u32)f2bf(hi2f(ou) + r1) << 16);
        *op = pk;
    }
}

// ---------------------------------------------------------------------------
extern "C" void kernel_launch(void* const* d_in, const int* in_sizes, int n_in,
                              void* d_out, int out_size, void* d_ws, size_t ws_size,
                              hipStream_t stream) {
    const void* feat = d_in[0];
    const int* src  = (const int*)d_in[1];
    const int* dst  = (const int*)d_in[2];
    const void* Wq = d_in[3]; const void* bq = d_in[4];
    const void* Wk = d_in[5]; const void* bk = d_in[6];
    const void* Wv = d_in[7]; const void* bv = d_in[8];
    const void* Ws = d_in[9]; const void* bs = d_in[10];

    const int N = in_sizes[0] / INF;   // 50000
    const int E = in_sizes[1];         // 800000

    u16* qb = (u16*)d_ws;
    u16* kb = qb + (size_t)N * OUTF;
    u16* vb = kb + (size_t)N * OUTF;
    u16* Wcat = vb + (size_t)N * OUTF;               // 512*128 bf16 = 128 KB
    float* bcat = (float*)(Wcat + 512 * INF);        // 2 KB
    int* counts  = (int*)(bcat + 512);  // N
    int* counter = counts + N;          // 1 (zeroed together with counts)
    int* start   = counter + 1;         // N
    int* cursor  = start + N;           // N
    int* srcs    = cursor + N;          // E
    int* flag    = srcs + E;            // 1

    (void)hipMemsetAsync(counts, 0, (size_t)(N + 1) * sizeof(int), stream);
    prep_kernel<<<2, 256, 0, stream>>>((const u32*)feat, Wq, bq, Wk, bk, Wv, bv, Ws, bs,
                                       Wcat, bcat, flag);
    proj_kernel<<<(N + 63) / 64, 256, 0, stream>>>(feat, Wcat, bcat, qb, kb, vb,
                                                   d_out, flag, N);
    count_kernel<<<(E + 255) / 256, 256, 0, stream>>>(dst, counts, E);
    alloc_kernel<<<(N + 255) / 256, 256, 0, stream>>>(counts, start, cursor, counter, N);
    scatter_kernel<<<(E + 255) / 256, 256, 0, stream>>>(dst, src, cursor, srcs, E);
    attn_kernel<<<(N + 3) / 4, 256, 0, stream>>>(qb, kb, vb, start, counts, srcs,
                                                 d_out, flag, N);
}